// Round 3
// baseline (267.285 us; speedup 1.0000x reference)
//
#include <hip/hip_runtime.h>
#include <hip/hip_bf16.h>

#define EPSF 1e-5f

typedef __attribute__((ext_vector_type(8))) short bf16x8;
typedef __attribute__((ext_vector_type(4))) float f32x4;
typedef __attribute__((ext_vector_type(2))) unsigned int u32x2;
typedef __attribute__((ext_vector_type(4))) unsigned int u32x4;
typedef __attribute__((ext_vector_type(4))) int i32x4;

constexpr int B_ = 2, N_ = 16384;
constexpr int HSTR = 72;   // hbuf row stride (bf16 elems)
constexpr int RSTR = 72;
constexpr int PPW  = 2;    // points per wave  (was 4)
constexpr int NW   = 8;    // waves per block  (was 4)
constexpr int PPB  = 16;   // points per block (unchanged)
constexpr size_t PP_BYTES = (size_t)B_ * N_ * 16;   // 512 KiB padded points

__device__ __forceinline__ short f2bf(float f) {
    __hip_bfloat16 h = __float2bfloat16(f);
    short s; __builtin_memcpy(&s, &h, 2); return s;
}
// packed f32x2 -> bf16x2 (v_cvt_pk_bf16_f32)
__device__ __forceinline__ unsigned int pkbf(float a, float b) {
    float2 f2; f2.x = a; f2.y = b;
    __hip_bfloat162 h = __float22bfloat162_rn(f2);
    unsigned int u; __builtin_memcpy(&u, &h, 4); return u;
}

// prep: points -> padded float4 (one dwordx4 gather instead of 3 divergent dwords)
__global__ __launch_bounds__(256) void prep_points(
    const float* __restrict__ pts, float* __restrict__ pp)
{
    const int i = blockIdx.x * 256 + threadIdx.x;
    if (i < B_ * N_) {
        f32x4 o = { pts[3 * i], pts[3 * i + 1], pts[3 * i + 2], 0.f };
        ((f32x4*)pp)[i] = o;
    }
}

// bridgenet9 vs bridgenet8 (residency-driven, R2 post-mortem):
//  - GEOMETRY: 8 waves x 2 points (512 thr), PPB=16, same 2048-block grid.
//    Measured residency was 1.56 waves/SIMD vs a 16-wave/CU cap: block
//    lifetime (4-point serial chain) + straggler variance ate occupancy.
//    Halving the per-wave chain and doubling waves/block attacks that.
//    LDS 55.5 KB -> 2 blocks/CU -> same 16-wave cap; VGPR held <=128 via
//    __launch_bounds__(512,4) so the cap stays LDS-defined.
//  - resid prefetched inside LOADD (was the one in-iteration load left).
//  - s_setprio(1) around MFMA clusters (waves at heterogeneous phases).
//  - phase D: waves 0..3 only (identical math to bridgenet8).
//  - kept: int4 index loads, XCD batch-affinity swizzle, coop staging.
template<bool PAD>
__global__ __launch_bounds__(512, 4) void bridgenet9(
    const float* __restrict__ points,     // raw (PAD=false)
    const float* __restrict__ pp,         // padded float4 (PAD=true)
    const float* __restrict__ features,
    const int*   __restrict__ gidx,
    const float* __restrict__ Wpos,
    const float* __restrict__ bposv,
    const float* __restrict__ bn1g, const float* __restrict__ bn1b,
    const float* __restrict__ bn1m, const float* __restrict__ bn1v,
    const float* __restrict__ Wgcm,
    const float* __restrict__ bgcm,
    const float* __restrict__ bn2g, const float* __restrict__ bn2b,
    const float* __restrict__ bn2m, const float* __restrict__ bn2v,
    const float* __restrict__ Watt,
    const float* __restrict__ batt,
    const float* __restrict__ Wout,
    const float* __restrict__ bout,
    const float* __restrict__ lng, const float* __restrict__ lnb,
    float* __restrict__ out)
{
    __shared__ __align__(16) short hbuf[NW][32 * HSTR];       // 36864 B
    __shared__ __align__(16) short resstage[PPB * RSTR];      //  2304 B
    __shared__ __align__(16) short wb2[8 * 64 * 8];           //  8192 B
    __shared__ __align__(16) short wb3[8 * 64 * 8];           //  8192 B

    const int t    = threadIdx.x;
    const int w    = t >> 6;
    const int l    = t & 63;
    const int l15  = l & 15;
    const int quad = l >> 4;
    const int c4   = l15 * 4;

    // ---- XCD batch-affinity swizzle (round-robin wg%8 -> XCD) ----
    const int wg  = blockIdx.x;
    const int blk = ((wg & 7) >> 2) * 1024 + (wg >> 3) * 4 + (wg & 3);

    // ---- cooperative weight staging: 16 frag-sets, 2 per wave ----
    {
        #pragma unroll
        for (int u = 0; u < 2; ++u) {
            const int s  = w * 2 + u;          // 0..15
            const int nt = (s >> 1) & 3, ks = s & 1;
            const float* src = (s < 8 ? Wgcm : Wout) + (c4 + nt) * 64 + ks * 32 + quad * 8;
            const f32x4 w0 = *(const f32x4*)src;
            const f32x4 w1 = *(const f32x4*)(src + 4);
            bf16x8 f;
            #pragma unroll
            for (int j = 0; j < 4; ++j) {
                f[j]     = f2bf(w0[j]);
                f[j + 4] = f2bf(w1[j]);
            }
            short* dst = (s < 8 ? wb2 : wb3);
            *(bf16x8*)&dst[((s & 7) * 64 + l) * 8] = f;
        }
    }

    // ---- per-wave constant state ----
    bf16x8 bposf[4];
    #pragma unroll
    for (int nt = 0; nt < 4; ++nt) {
        const int c = c4 + nt;
        #pragma unroll
        for (int j = 0; j < 8; ++j) {
            const int g = quad * 8 + j;
            bposf[nt][j] = f2bf(g < 10 ? Wpos[c * 10 + g] : 0.f);
        }
    }
    f32x4 ps1, pb1, ps2, pb2;
    {
        const f32x4 g1 = *(const f32x4*)(bn1g + c4);
        const f32x4 b1 = *(const f32x4*)(bn1b + c4);
        const f32x4 m1 = *(const f32x4*)(bn1m + c4);
        const f32x4 v1 = *(const f32x4*)(bn1v + c4);
        const f32x4 bp = *(const f32x4*)(bposv + c4);
        const f32x4 g2 = *(const f32x4*)(bn2g + c4);
        const f32x4 b2 = *(const f32x4*)(bn2b + c4);
        const f32x4 m2 = *(const f32x4*)(bn2m + c4);
        const f32x4 v2 = *(const f32x4*)(bn2v + c4);
        const f32x4 bg = *(const f32x4*)(bgcm + c4);
        #pragma unroll
        for (int j = 0; j < 4; ++j) {
            ps1[j] = g1[j] * rsqrtf(v1[j] + EPSF);
            pb1[j] = ps1[j] * (bp[j] - m1[j]) + b1[j];
            ps2[j] = g2[j] * rsqrtf(v2[j] + EPSF);
            pb2[j] = ps2[j] * (bg[j] - m2[j]) + b2[j];
        }
    }
    float wat[2][4];
    #pragma unroll
    for (int mt = 0; mt < 2; ++mt)
        #pragma unroll
        for (int r = 0; r < 4; ++r)
            wat[mt][r] = Watt[mt * 16 + quad * 4 + r];
    const float battv = batt[0];

    const f32x4 zero4 = {0.f, 0.f, 0.f, 0.f};
    short* hb = hbuf[w];
    const int base = blk * PPB + w * PPW;
    const int bb   = (blk >> 10) * N_;

    // ---- pipeline helpers ----
    auto LOADI = [&](int pt, i32x4 (&gi)[2]) {
        gi[0] = *(const i32x4*)(gidx + (size_t)pt * 32 + quad * 4);
        gi[1] = *(const i32x4*)(gidx + (size_t)pt * 32 + 16 + quad * 4);
    };
    // loads everything point pt needs (incl. resid), packs geo A-frags
    auto LOADD = [&](int pt, const i32x4 (&gi)[2],
                     f32x4 (&f4)[2][4], bf16x8 (&ageo)[2], f32x4& resid) {
        #pragma unroll
        for (int mt = 0; mt < 2; ++mt)
            #pragma unroll
            for (int r = 0; r < 4; ++r)
                f4[mt][r] = *(const f32x4*)(features + (size_t)(bb + gi[mt][r]) * 64 + c4);
        resid = *(const f32x4*)(features + (size_t)pt * 64 + c4);
        int gv[2];
        gv[0] = gidx[(size_t)pt * 32 + l15];
        gv[1] = gidx[(size_t)pt * 32 + 16 + l15];
        float xi0, xi1, xi2, px[2], py[2], pz[2];
        if (PAD) {
            const f32x4 x4 = *(const f32x4*)(pp + (size_t)pt * 4);
            xi0 = x4[0]; xi1 = x4[1]; xi2 = x4[2];
            #pragma unroll
            for (int mt = 0; mt < 2; ++mt) {
                const f32x4 p4 = *(const f32x4*)(pp + (size_t)(bb + gv[mt]) * 4);
                px[mt] = p4[0]; py[mt] = p4[1]; pz[mt] = p4[2];
            }
        } else {
            xi0 = points[(size_t)pt * 3];
            xi1 = points[(size_t)pt * 3 + 1];
            xi2 = points[(size_t)pt * 3 + 2];
            #pragma unroll
            for (int mt = 0; mt < 2; ++mt) {
                const float* ppt = points + (size_t)(bb + gv[mt]) * 3;
                px[mt] = ppt[0]; py[mt] = ppt[1]; pz[mt] = ppt[2];
            }
        }
        #pragma unroll
        for (int mt = 0; mt < 2; ++mt) {
            const float dx = xi0 - px[mt], dy = xi1 - py[mt], dz = xi2 - pz[mt];
            const float dist = sqrtf(dx * dx + dy * dy + dz * dz);
            u32x4 u = {0u, 0u, 0u, 0u};
            if (quad == 0) {
                u[0] = pkbf(xi0, xi1); u[1] = pkbf(xi2, px[mt]);
                u[2] = pkbf(py[mt], pz[mt]); u[3] = pkbf(dx, dy);
            } else if (quad == 1) {
                u[0] = pkbf(dz, dist);
            }
            __builtin_memcpy(&ageo[mt], &u, 16);
        }
    };

    // ---- prologue: fill pipeline for points base+0 / base+1 ----
    i32x4 giC[2], giN[2];
    LOADI(base, giC);
    LOADI(base + 1, giN);
    f32x4  f4c[2][4];
    bf16x8 ageoc[2];
    f32x4  residc;
    LOADD(base, giC, f4c, ageoc, residc);

    __syncthreads();   // weight LDS ready

    #pragma unroll
    for (int i = 0; i < PPW; ++i) {
        const int pt = base + i;
        (void)pt;

        // --- pipeline stage: next point's data under this point's compute ---
        f32x4  f4n[2][4];
        bf16x8 ageon[2];
        f32x4  residn;
        if (i + 1 < PPW) LOADD(base + i + 1, giN, f4n, ageon, residn);

        // --- pos-MLP MFMA (inputs already in registers) ---
        __builtin_amdgcn_s_setprio(1);
        f32x4 acc1[2][4];
        #pragma unroll
        for (int mt = 0; mt < 2; ++mt)
            #pragma unroll
            for (int nt = 0; nt < 4; ++nt)
                acc1[mt][nt] = __builtin_amdgcn_mfma_f32_16x16x32_bf16(
                    ageoc[mt], bposf[nt], zero4, 0, 0, 0);
        __builtin_amdgcn_s_setprio(0);

        // --- epilogue 1: bn1+relu + feature add, packed converts, b64 writes ---
        #pragma unroll
        for (int mt = 0; mt < 2; ++mt)
            #pragma unroll
            for (int r = 0; r < 4; ++r) {
                const int k = mt * 16 + quad * 4 + r;
                float v[4];
                #pragma unroll
                for (int j = 0; j < 4; ++j)
                    v[j] = f4c[mt][r][j] + fmaxf(ps1[j] * acc1[mt][j][r] + pb1[j], 0.f);
                u32x2 hv = { pkbf(v[0], v[1]), pkbf(v[2], v[3]) };
                *(u32x2*)&hb[k * HSTR + c4] = hv;
            }

        // --- GCM: A-frags from LDS, B-frags from LDS, 16 MFMAs ---
        bf16x8 a2[2][2];
        #pragma unroll
        for (int mt = 0; mt < 2; ++mt)
            #pragma unroll
            for (int ks = 0; ks < 2; ++ks)
                a2[mt][ks] = *(const bf16x8*)&hb[(mt * 16 + l15) * HSTR + ks * 32 + quad * 8];
        __builtin_amdgcn_s_setprio(1);
        f32x4 acc2[2][4];
        #pragma unroll
        for (int nt = 0; nt < 4; ++nt) {
            const bf16x8 b0 = *(const bf16x8*)&wb2[((nt * 2 + 0) * 64 + l) * 8];
            const bf16x8 b1 = *(const bf16x8*)&wb2[((nt * 2 + 1) * 64 + l) * 8];
            #pragma unroll
            for (int mt = 0; mt < 2; ++mt) {
                f32x4 a = __builtin_amdgcn_mfma_f32_16x16x32_bf16(a2[mt][0], b0, zero4, 0, 0, 0);
                acc2[mt][nt] = __builtin_amdgcn_mfma_f32_16x16x32_bf16(a2[mt][1], b1, a, 0, 0, 0);
            }
        }
        __builtin_amdgcn_s_setprio(0);

        // --- epilogue 2: bn2+relu, attention softmax (over channels), pool ---
        float res[4];
        {
            float sp[4], mk[4];
            #pragma unroll
            for (int nt = 0; nt < 4; ++nt) {
                sp[nt] = 0.f; mk[nt] = 0.f;
                #pragma unroll
                for (int mt = 0; mt < 2; ++mt)
                    #pragma unroll
                    for (int r = 0; r < 4; ++r) {
                        const float h2 = fmaxf(ps2[nt] * acc2[mt][nt][r] + pb2[nt], 0.f);
                        sp[nt] += h2 * wat[mt][r];
                        mk[nt] = fmaxf(mk[nt], h2);
                    }
                sp[nt] += __shfl_xor(sp[nt], 16);
                sp[nt] += __shfl_xor(sp[nt], 32);
                mk[nt] = fmaxf(mk[nt], __shfl_xor(mk[nt], 16));
                mk[nt] = fmaxf(mk[nt], __shfl_xor(mk[nt], 32));
            }
            float e[4], s = 0.f;
            #pragma unroll
            for (int nt = 0; nt < 4; ++nt) { e[nt] = __expf(sp[nt] + battv); s += e[nt]; }
            #pragma unroll
            for (int o = 1; o < 16; o <<= 1) s += __shfl_xor(s, o);
            const float inv = 1.f / s;
            #pragma unroll
            for (int nt = 0; nt < 4; ++nt)
                res[nt] = e[nt] * inv * mk[nt] + residc[nt];
        }
        if (quad == 0) {
            u32x2 rv = { pkbf(res[0], res[1]), pkbf(res[2], res[3]) };
            *(u32x2*)&resstage[(w * PPW + i) * RSTR + c4] = rv;
        }

        // --- rotate pipeline registers ---
        if (i + 1 < PPW) {
            #pragma unroll
            for (int mt = 0; mt < 2; ++mt) {
                #pragma unroll
                for (int r = 0; r < 4; ++r) f4c[mt][r] = f4n[mt][r];
                ageoc[mt] = ageon[mt];
            }
            residc = residn;
        }
    }

    __syncthreads();

    // ---------- phase D: batched out-matmul + LayerNorm + relu (waves 0-3) ----
    if (w < 4) {
        const f32x4 lngv  = *(const f32x4*)(lng + c4);
        const f32x4 lnbv  = *(const f32x4*)(lnb + c4);
        const f32x4 boutv = *(const f32x4*)(bout + c4);
        bf16x8 a3[2];
        #pragma unroll
        for (int ks = 0; ks < 2; ++ks)
            a3[ks] = *(const bf16x8*)&resstage[l15 * RSTR + ks * 32 + quad * 8];
        f32x4 acc3[4];
        #pragma unroll
        for (int nt = 0; nt < 4; ++nt) {
            const bf16x8 b0 = *(const bf16x8*)&wb3[((nt * 2 + 0) * 64 + l) * 8];
            const bf16x8 b1 = *(const bf16x8*)&wb3[((nt * 2 + 1) * 64 + l) * 8];
            f32x4 a = __builtin_amdgcn_mfma_f32_16x16x32_bf16(a3[0], b0, zero4, 0, 0, 0);
            acc3[nt] = __builtin_amdgcn_mfma_f32_16x16x32_bf16(a3[1], b1, a, 0, 0, 0);
        }
        float y[4], s = 0.f;
        #pragma unroll
        for (int nt = 0; nt < 4; ++nt) { y[nt] = acc3[nt][w] + boutv[nt]; s += y[nt]; }
        #pragma unroll
        for (int o = 1; o < 16; o <<= 1) s += __shfl_xor(s, o);
        const float mu = s * (1.f / 64.f);
        float dv[4], v2 = 0.f;
        #pragma unroll
        for (int nt = 0; nt < 4; ++nt) { dv[nt] = y[nt] - mu; v2 += dv[nt] * dv[nt]; }
        #pragma unroll
        for (int o = 1; o < 16; o <<= 1) v2 += __shfl_xor(v2, o);
        const float rs = rsqrtf(v2 * (1.f / 64.f) + EPSF);
        const int pto = blk * PPB + quad * 4 + w;   // swizzle-corrected output index
        f32x4 ov;
        #pragma unroll
        for (int nt = 0; nt < 4; ++nt)
            ov[nt] = fmaxf(lngv[nt] * dv[nt] * rs + lnbv[nt], 0.f);
        *(f32x4*)(out + (size_t)pto * 64 + c4) = ov;
    }
}

extern "C" void kernel_launch(void* const* d_in, const int* in_sizes, int n_in,
                              void* d_out, int out_size, void* d_ws, size_t ws_size,
                              hipStream_t stream) {
    const float* points   = (const float*)d_in[0];
    const float* features = (const float*)d_in[1];
    const int*   gidxp    = (const int*)d_in[2];
    const bool   pad      = (ws_size >= PP_BYTES);
    float* pp = (float*)d_ws;
    if (pad) {
        hipLaunchKernelGGL(prep_points, dim3((B_ * N_ + 255) / 256), dim3(256), 0, stream,
                           points, pp);
        hipLaunchKernelGGL((bridgenet9<true>), dim3((B_ * N_) / PPB), dim3(512), 0, stream,
            points, pp, features, gidxp,
            (const float*)d_in[3],  (const float*)d_in[4],
            (const float*)d_in[5],  (const float*)d_in[6],  (const float*)d_in[7],  (const float*)d_in[8],
            (const float*)d_in[9],  (const float*)d_in[10],
            (const float*)d_in[11], (const float*)d_in[12], (const float*)d_in[13], (const float*)d_in[14],
            (const float*)d_in[15], (const float*)d_in[16],
            (const float*)d_in[17], (const float*)d_in[18],
            (const float*)d_in[19], (const float*)d_in[20],
            (float*)d_out);
    } else {
        hipLaunchKernelGGL((bridgenet9<false>), dim3((B_ * N_) / PPB), dim3(512), 0, stream,
            points, pp, features, gidxp,
            (const float*)d_in[3],  (const float*)d_in[4],
            (const float*)d_in[5],  (const float*)d_in[6],  (const float*)d_in[7],  (const float*)d_in[8],
            (const float*)d_in[9],  (const float*)d_in[10],
            (const float*)d_in[11], (const float*)d_in[12], (const float*)d_in[13], (const float*)d_in[14],
            (const float*)d_in[15], (const float*)d_in[16],
            (const float*)d_in[17], (const float*)d_in[18],
            (const float*)d_in[19], (const float*)d_in[20],
            (float*)d_out);
    }
}

// Round 4
// 203.277 us; speedup vs baseline: 1.3149x; 1.3149x over previous
//
#include <hip/hip_runtime.h>
#include <hip/hip_bf16.h>

#define EPSF 1e-5f

typedef __attribute__((ext_vector_type(8))) short bf16x8;
typedef __attribute__((ext_vector_type(4))) float f32x4;
typedef __attribute__((ext_vector_type(2))) unsigned int u32x2;
typedef __attribute__((ext_vector_type(4))) unsigned int u32x4;
typedef __attribute__((ext_vector_type(4))) int i32x4;

constexpr int B_ = 2, N_ = 16384;
constexpr int HSTR = 72;   // hbuf row stride (bf16 elems)
constexpr int RSTR = 72;
constexpr int PPW  = 2;    // points per wave
constexpr int NW   = 8;    // waves per block
constexpr int PPB  = 16;   // points per block
constexpr size_t PP_BYTES = (size_t)B_ * N_ * 16;   // 512 KiB padded points

__device__ __forceinline__ short f2bf(float f) {
    __hip_bfloat16 h = __float2bfloat16(f);
    short s; __builtin_memcpy(&s, &h, 2); return s;
}
// packed f32x2 -> bf16x2 (v_cvt_pk_bf16_f32)
__device__ __forceinline__ unsigned int pkbf(float a, float b) {
    float2 f2; f2.x = a; f2.y = b;
    __hip_bfloat162 h = __float22bfloat162_rn(f2);
    unsigned int u; __builtin_memcpy(&u, &h, 4); return u;
}

// prep: points -> padded float4 (one dwordx4 gather instead of 3 divergent dwords)
__global__ __launch_bounds__(256) void prep_points(
    const float* __restrict__ pts, float* __restrict__ pp)
{
    const int i = blockIdx.x * 256 + threadIdx.x;
    if (i < B_ * N_) {
        f32x4 o = { pts[3 * i], pts[3 * i + 1], pts[3 * i + 2], 0.f };
        ((f32x4*)pp)[i] = o;
    }
}

// bridgenet10 vs bridgenet9 (R3 post-mortem):
//  - ONLY change: __launch_bounds__(512, 2) instead of (512, 4).
//    R3's (512,4) capped the unified VGPR+AGPR budget at 128 -> the ~120-VGPR
//    pipelined body + MFMA accs spilled to scratch (WRITE_SIZE 8->327 MB,
//    FETCH 33->250 MB, dur 83->175 us). (512,2) caps at 256: no spill.
//  - R3 PROVED the geometry lever: ~1.6 blocks resident/CU regardless of
//    block size (R0-R2: 1.6x4 waves = 20% occ; R3: 1.6x8 = 40% occ).
//    8-wave blocks bypass the block-residency limit; with spills gone the
//    extra waves should turn into VALUBusy (measured VALU floor ~34 us).
//  - kept: 8 waves x 2 points, 2-deep point pipeline, int4 index loads,
//    XCD batch-affinity swizzle, coop weight staging, setprio on MFMA,
//    phase D on waves 0..3.
template<bool PAD>
__global__ __launch_bounds__(512, 2) void bridgenet10(
    const float* __restrict__ points,     // raw (PAD=false)
    const float* __restrict__ pp,         // padded float4 (PAD=true)
    const float* __restrict__ features,
    const int*   __restrict__ gidx,
    const float* __restrict__ Wpos,
    const float* __restrict__ bposv,
    const float* __restrict__ bn1g, const float* __restrict__ bn1b,
    const float* __restrict__ bn1m, const float* __restrict__ bn1v,
    const float* __restrict__ Wgcm,
    const float* __restrict__ bgcm,
    const float* __restrict__ bn2g, const float* __restrict__ bn2b,
    const float* __restrict__ bn2m, const float* __restrict__ bn2v,
    const float* __restrict__ Watt,
    const float* __restrict__ batt,
    const float* __restrict__ Wout,
    const float* __restrict__ bout,
    const float* __restrict__ lng, const float* __restrict__ lnb,
    float* __restrict__ out)
{
    __shared__ __align__(16) short hbuf[NW][32 * HSTR];       // 36864 B
    __shared__ __align__(16) short resstage[PPB * RSTR];      //  2304 B
    __shared__ __align__(16) short wb2[8 * 64 * 8];           //  8192 B
    __shared__ __align__(16) short wb3[8 * 64 * 8];           //  8192 B

    const int t    = threadIdx.x;
    const int w    = t >> 6;
    const int l    = t & 63;
    const int l15  = l & 15;
    const int quad = l >> 4;
    const int c4   = l15 * 4;

    // ---- XCD batch-affinity swizzle (round-robin wg%8 -> XCD) ----
    const int wg  = blockIdx.x;
    const int blk = ((wg & 7) >> 2) * 1024 + (wg >> 3) * 4 + (wg & 3);

    // ---- cooperative weight staging: 16 frag-sets, 2 per wave ----
    {
        #pragma unroll
        for (int u = 0; u < 2; ++u) {
            const int s  = w * 2 + u;          // 0..15
            const int nt = (s >> 1) & 3, ks = s & 1;
            const float* src = (s < 8 ? Wgcm : Wout) + (c4 + nt) * 64 + ks * 32 + quad * 8;
            const f32x4 w0 = *(const f32x4*)src;
            const f32x4 w1 = *(const f32x4*)(src + 4);
            bf16x8 f;
            #pragma unroll
            for (int j = 0; j < 4; ++j) {
                f[j]     = f2bf(w0[j]);
                f[j + 4] = f2bf(w1[j]);
            }
            short* dst = (s < 8 ? wb2 : wb3);
            *(bf16x8*)&dst[((s & 7) * 64 + l) * 8] = f;
        }
    }

    // ---- per-wave constant state ----
    bf16x8 bposf[4];
    #pragma unroll
    for (int nt = 0; nt < 4; ++nt) {
        const int c = c4 + nt;
        #pragma unroll
        for (int j = 0; j < 8; ++j) {
            const int g = quad * 8 + j;
            bposf[nt][j] = f2bf(g < 10 ? Wpos[c * 10 + g] : 0.f);
        }
    }
    f32x4 ps1, pb1, ps2, pb2;
    {
        const f32x4 g1 = *(const f32x4*)(bn1g + c4);
        const f32x4 b1 = *(const f32x4*)(bn1b + c4);
        const f32x4 m1 = *(const f32x4*)(bn1m + c4);
        const f32x4 v1 = *(const f32x4*)(bn1v + c4);
        const f32x4 bp = *(const f32x4*)(bposv + c4);
        const f32x4 g2 = *(const f32x4*)(bn2g + c4);
        const f32x4 b2 = *(const f32x4*)(bn2b + c4);
        const f32x4 m2 = *(const f32x4*)(bn2m + c4);
        const f32x4 v2 = *(const f32x4*)(bn2v + c4);
        const f32x4 bg = *(const f32x4*)(bgcm + c4);
        #pragma unroll
        for (int j = 0; j < 4; ++j) {
            ps1[j] = g1[j] * rsqrtf(v1[j] + EPSF);
            pb1[j] = ps1[j] * (bp[j] - m1[j]) + b1[j];
            ps2[j] = g2[j] * rsqrtf(v2[j] + EPSF);
            pb2[j] = ps2[j] * (bg[j] - m2[j]) + b2[j];
        }
    }
    float wat[2][4];
    #pragma unroll
    for (int mt = 0; mt < 2; ++mt)
        #pragma unroll
        for (int r = 0; r < 4; ++r)
            wat[mt][r] = Watt[mt * 16 + quad * 4 + r];
    const float battv = batt[0];

    const f32x4 zero4 = {0.f, 0.f, 0.f, 0.f};
    short* hb = hbuf[w];
    const int base = blk * PPB + w * PPW;
    const int bb   = (blk >> 10) * N_;

    // ---- pipeline helpers ----
    auto LOADI = [&](int pt, i32x4 (&gi)[2]) {
        gi[0] = *(const i32x4*)(gidx + (size_t)pt * 32 + quad * 4);
        gi[1] = *(const i32x4*)(gidx + (size_t)pt * 32 + 16 + quad * 4);
    };
    // loads everything point pt needs (incl. resid), packs geo A-frags
    auto LOADD = [&](int pt, const i32x4 (&gi)[2],
                     f32x4 (&f4)[2][4], bf16x8 (&ageo)[2], f32x4& resid) {
        #pragma unroll
        for (int mt = 0; mt < 2; ++mt)
            #pragma unroll
            for (int r = 0; r < 4; ++r)
                f4[mt][r] = *(const f32x4*)(features + (size_t)(bb + gi[mt][r]) * 64 + c4);
        resid = *(const f32x4*)(features + (size_t)pt * 64 + c4);
        int gv[2];
        gv[0] = gidx[(size_t)pt * 32 + l15];
        gv[1] = gidx[(size_t)pt * 32 + 16 + l15];
        float xi0, xi1, xi2, px[2], py[2], pz[2];
        if (PAD) {
            const f32x4 x4 = *(const f32x4*)(pp + (size_t)pt * 4);
            xi0 = x4[0]; xi1 = x4[1]; xi2 = x4[2];
            #pragma unroll
            for (int mt = 0; mt < 2; ++mt) {
                const f32x4 p4 = *(const f32x4*)(pp + (size_t)(bb + gv[mt]) * 4);
                px[mt] = p4[0]; py[mt] = p4[1]; pz[mt] = p4[2];
            }
        } else {
            xi0 = points[(size_t)pt * 3];
            xi1 = points[(size_t)pt * 3 + 1];
            xi2 = points[(size_t)pt * 3 + 2];
            #pragma unroll
            for (int mt = 0; mt < 2; ++mt) {
                const float* ppt = points + (size_t)(bb + gv[mt]) * 3;
                px[mt] = ppt[0]; py[mt] = ppt[1]; pz[mt] = ppt[2];
            }
        }
        #pragma unroll
        for (int mt = 0; mt < 2; ++mt) {
            const float dx = xi0 - px[mt], dy = xi1 - py[mt], dz = xi2 - pz[mt];
            const float dist = sqrtf(dx * dx + dy * dy + dz * dz);
            u32x4 u = {0u, 0u, 0u, 0u};
            if (quad == 0) {
                u[0] = pkbf(xi0, xi1); u[1] = pkbf(xi2, px[mt]);
                u[2] = pkbf(py[mt], pz[mt]); u[3] = pkbf(dx, dy);
            } else if (quad == 1) {
                u[0] = pkbf(dz, dist);
            }
            __builtin_memcpy(&ageo[mt], &u, 16);
        }
    };

    // ---- prologue: fill pipeline for points base+0 / base+1 ----
    i32x4 giC[2], giN[2];
    LOADI(base, giC);
    LOADI(base + 1, giN);
    f32x4  f4c[2][4];
    bf16x8 ageoc[2];
    f32x4  residc;
    LOADD(base, giC, f4c, ageoc, residc);

    __syncthreads();   // weight LDS ready

    #pragma unroll
    for (int i = 0; i < PPW; ++i) {
        // --- pipeline stage: next point's data under this point's compute ---
        f32x4  f4n[2][4];
        bf16x8 ageon[2];
        f32x4  residn;
        if (i + 1 < PPW) LOADD(base + i + 1, giN, f4n, ageon, residn);

        // --- pos-MLP MFMA (inputs already in registers) ---
        __builtin_amdgcn_s_setprio(1);
        f32x4 acc1[2][4];
        #pragma unroll
        for (int mt = 0; mt < 2; ++mt)
            #pragma unroll
            for (int nt = 0; nt < 4; ++nt)
                acc1[mt][nt] = __builtin_amdgcn_mfma_f32_16x16x32_bf16(
                    ageoc[mt], bposf[nt], zero4, 0, 0, 0);
        __builtin_amdgcn_s_setprio(0);

        // --- epilogue 1: bn1+relu + feature add, packed converts, b64 writes ---
        #pragma unroll
        for (int mt = 0; mt < 2; ++mt)
            #pragma unroll
            for (int r = 0; r < 4; ++r) {
                const int k = mt * 16 + quad * 4 + r;
                float v[4];
                #pragma unroll
                for (int j = 0; j < 4; ++j)
                    v[j] = f4c[mt][r][j] + fmaxf(ps1[j] * acc1[mt][j][r] + pb1[j], 0.f);
                u32x2 hv = { pkbf(v[0], v[1]), pkbf(v[2], v[3]) };
                *(u32x2*)&hb[k * HSTR + c4] = hv;
            }

        // --- GCM: A-frags from LDS, B-frags from LDS, 16 MFMAs ---
        bf16x8 a2[2][2];
        #pragma unroll
        for (int mt = 0; mt < 2; ++mt)
            #pragma unroll
            for (int ks = 0; ks < 2; ++ks)
                a2[mt][ks] = *(const bf16x8*)&hb[(mt * 16 + l15) * HSTR + ks * 32 + quad * 8];
        __builtin_amdgcn_s_setprio(1);
        f32x4 acc2[2][4];
        #pragma unroll
        for (int nt = 0; nt < 4; ++nt) {
            const bf16x8 b0 = *(const bf16x8*)&wb2[((nt * 2 + 0) * 64 + l) * 8];
            const bf16x8 b1 = *(const bf16x8*)&wb2[((nt * 2 + 1) * 64 + l) * 8];
            #pragma unroll
            for (int mt = 0; mt < 2; ++mt) {
                f32x4 a = __builtin_amdgcn_mfma_f32_16x16x32_bf16(a2[mt][0], b0, zero4, 0, 0, 0);
                acc2[mt][nt] = __builtin_amdgcn_mfma_f32_16x16x32_bf16(a2[mt][1], b1, a, 0, 0, 0);
            }
        }
        __builtin_amdgcn_s_setprio(0);

        // --- epilogue 2: bn2+relu, attention softmax (shift-invariant), pool ---
        float res[4];
        {
            float sp[4], mk[4];
            #pragma unroll
            for (int nt = 0; nt < 4; ++nt) {
                sp[nt] = 0.f; mk[nt] = 0.f;
                #pragma unroll
                for (int mt = 0; mt < 2; ++mt)
                    #pragma unroll
                    for (int r = 0; r < 4; ++r) {
                        const float h2 = fmaxf(ps2[nt] * acc2[mt][nt][r] + pb2[nt], 0.f);
                        sp[nt] += h2 * wat[mt][r];
                        mk[nt] = fmaxf(mk[nt], h2);
                    }
                sp[nt] += __shfl_xor(sp[nt], 16);
                sp[nt] += __shfl_xor(sp[nt], 32);
                mk[nt] = fmaxf(mk[nt], __shfl_xor(mk[nt], 16));
                mk[nt] = fmaxf(mk[nt], __shfl_xor(mk[nt], 32));
            }
            float e[4], s = 0.f;
            #pragma unroll
            for (int nt = 0; nt < 4; ++nt) { e[nt] = __expf(sp[nt] + battv); s += e[nt]; }
            #pragma unroll
            for (int o = 1; o < 16; o <<= 1) s += __shfl_xor(s, o);
            const float inv = 1.f / s;
            #pragma unroll
            for (int nt = 0; nt < 4; ++nt)
                res[nt] = e[nt] * inv * mk[nt] + residc[nt];
        }
        if (quad == 0) {
            u32x2 rv = { pkbf(res[0], res[1]), pkbf(res[2], res[3]) };
            *(u32x2*)&resstage[(w * PPW + i) * RSTR + c4] = rv;
        }

        // --- rotate pipeline registers ---
        if (i + 1 < PPW) {
            #pragma unroll
            for (int mt = 0; mt < 2; ++mt) {
                #pragma unroll
                for (int r = 0; r < 4; ++r) f4c[mt][r] = f4n[mt][r];
                ageoc[mt] = ageon[mt];
            }
            residc = residn;
        }
    }

    __syncthreads();

    // ---------- phase D: batched out-matmul + LayerNorm + relu (waves 0-3) ----
    if (w < 4) {
        const f32x4 lngv  = *(const f32x4*)(lng + c4);
        const f32x4 lnbv  = *(const f32x4*)(lnb + c4);
        const f32x4 boutv = *(const f32x4*)(bout + c4);
        bf16x8 a3[2];
        #pragma unroll
        for (int ks = 0; ks < 2; ++ks)
            a3[ks] = *(const bf16x8*)&resstage[l15 * RSTR + ks * 32 + quad * 8];
        f32x4 acc3[4];
        #pragma unroll
        for (int nt = 0; nt < 4; ++nt) {
            const bf16x8 b0 = *(const bf16x8*)&wb3[((nt * 2 + 0) * 64 + l) * 8];
            const bf16x8 b1 = *(const bf16x8*)&wb3[((nt * 2 + 1) * 64 + l) * 8];
            f32x4 a = __builtin_amdgcn_mfma_f32_16x16x32_bf16(a3[0], b0, zero4, 0, 0, 0);
            acc3[nt] = __builtin_amdgcn_mfma_f32_16x16x32_bf16(a3[1], b1, a, 0, 0, 0);
        }
        float y[4], s = 0.f;
        #pragma unroll
        for (int nt = 0; nt < 4; ++nt) { y[nt] = acc3[nt][w] + boutv[nt]; s += y[nt]; }
        #pragma unroll
        for (int o = 1; o < 16; o <<= 1) s += __shfl_xor(s, o);
        const float mu = s * (1.f / 64.f);
        float dv[4], v2 = 0.f;
        #pragma unroll
        for (int nt = 0; nt < 4; ++nt) { dv[nt] = y[nt] - mu; v2 += dv[nt] * dv[nt]; }
        #pragma unroll
        for (int o = 1; o < 16; o <<= 1) v2 += __shfl_xor(v2, o);
        const float rs = rsqrtf(v2 * (1.f / 64.f) + EPSF);
        const int pto = blk * PPB + quad * 4 + w;   // swizzle-corrected output index
        f32x4 ov;
        #pragma unroll
        for (int nt = 0; nt < 4; ++nt)
            ov[nt] = fmaxf(lngv[nt] * dv[nt] * rs + lnbv[nt], 0.f);
        *(f32x4*)(out + (size_t)pto * 64 + c4) = ov;
    }
}

extern "C" void kernel_launch(void* const* d_in, const int* in_sizes, int n_in,
                              void* d_out, int out_size, void* d_ws, size_t ws_size,
                              hipStream_t stream) {
    const float* points   = (const float*)d_in[0];
    const float* features = (const float*)d_in[1];
    const int*   gidxp    = (const int*)d_in[2];
    const bool   pad      = (ws_size >= PP_BYTES);
    float* pp = (float*)d_ws;
    if (pad) {
        hipLaunchKernelGGL(prep_points, dim3((B_ * N_ + 255) / 256), dim3(256), 0, stream,
                           points, pp);
        hipLaunchKernelGGL((bridgenet10<true>), dim3((B_ * N_) / PPB), dim3(512), 0, stream,
            points, pp, features, gidxp,
            (const float*)d_in[3],  (const float*)d_in[4],
            (const float*)d_in[5],  (const float*)d_in[6],  (const float*)d_in[7],  (const float*)d_in[8],
            (const float*)d_in[9],  (const float*)d_in[10],
            (const float*)d_in[11], (const float*)d_in[12], (const float*)d_in[13], (const float*)d_in[14],
            (const float*)d_in[15], (const float*)d_in[16],
            (const float*)d_in[17], (const float*)d_in[18],
            (const float*)d_in[19], (const float*)d_in[20],
            (float*)d_out);
    } else {
        hipLaunchKernelGGL((bridgenet10<false>), dim3((B_ * N_) / PPB), dim3(512), 0, stream,
            points, pp, features, gidxp,
            (const float*)d_in[3],  (const float*)d_in[4],
            (const float*)d_in[5],  (const float*)d_in[6],  (const float*)d_in[7],  (const float*)d_in[8],
            (const float*)d_in[9],  (const float*)d_in[10],
            (const float*)d_in[11], (const float*)d_in[12], (const float*)d_in[13], (const float*)d_in[14],
            (const float*)d_in[15], (const float*)d_in[16],
            (const float*)d_in[17], (const float*)d_in[18],
            (const float*)d_in[19], (const float*)d_in[20],
            (float*)d_out);
    }
}

// Round 5
// 163.272 us; speedup vs baseline: 1.6371x; 1.2450x over previous
//
#include <hip/hip_runtime.h>
#include <hip/hip_bf16.h>

#define EPSF 1e-5f

typedef __attribute__((ext_vector_type(8))) short bf16x8;
typedef __attribute__((ext_vector_type(4))) float f32x4;
typedef __attribute__((ext_vector_type(2))) unsigned int u32x2;
typedef __attribute__((ext_vector_type(4))) unsigned int u32x4;
typedef __attribute__((ext_vector_type(4))) int i32x4;

constexpr int B_ = 2, N_ = 16384;
constexpr int HSTR = 72;   // hbuf row stride (bf16 elems)
constexpr int RSTR = 72;
constexpr int PPW  = 8;    // points per wave   (was 2)
constexpr int NW   = 8;    // waves per block
constexpr int PPB  = 64;   // points per block  (was 16)
constexpr int NWG  = (B_ * N_) / PPB;   // 512 blocks
constexpr int HALF = NWG / 2;           // blocks per batch
constexpr size_t PP_BYTES = (size_t)B_ * N_ * 16;   // 512 KiB padded points

__device__ __forceinline__ short f2bf(float f) {
    __hip_bfloat16 h = __float2bfloat16(f);
    short s; __builtin_memcpy(&s, &h, 2); return s;
}
// packed f32x2 -> bf16x2 (v_cvt_pk_bf16_f32)
__device__ __forceinline__ unsigned int pkbf(float a, float b) {
    float2 f2; f2.x = a; f2.y = b;
    __hip_bfloat162 h = __float22bfloat162_rn(f2);
    unsigned int u; __builtin_memcpy(&u, &h, 4); return u;
}

// prep: points -> padded float4 (one dwordx4 gather instead of 3 divergent dwords)
__global__ __launch_bounds__(256) void prep_points(
    const float* __restrict__ pts, float* __restrict__ pp)
{
    const int i = blockIdx.x * 256 + threadIdx.x;
    if (i < B_ * N_) {
        f32x4 o = { pts[3 * i], pts[3 * i + 1], pts[3 * i + 2], 0.f };
        ((f32x4*)pp)[i] = o;
    }
}

// bridgenet11 vs bridgenet10 (R4 post-mortem):
//  - GEOMETRY: PPB=64 (512 blocks), 8 waves x PPW=8. Five rounds of data fit
//    two models -- (a) ~6.5 resident waves/CU -> minimize wave count x fixed
//    cost (F~6.3us/wave, P~2.5us/point); (b) WG dispatch rate ~20-25/us ->
//    minimize block count. BOTH prescribe fewer/longer waves & blocks:
//    4096 waves x 26us or 512 blocks/23us -> ~50-65us predicted.
//  - LDS 62.4 KB (hbuf 36.9K + resstage 9.2K + wb2/wb3 16K) -> 2 blocks/CU,
//    entire grid resident-capable.
//  - phase D: 4 groups of 16 points; wave w -> group w>>1, rows (w&1)*2+{0,1}.
//  - kept: 2-deep point pipeline, int4 idx loads + LOADI 2-ahead, XCD
//    batch-affinity swizzle (generalized to NWG), coop staging, setprio,
//    __launch_bounds__(512,2) (256-VGPR cap, R4-verified no spill).
template<bool PAD>
__global__ __launch_bounds__(512, 2) void bridgenet11(
    const float* __restrict__ points,     // raw (PAD=false)
    const float* __restrict__ pp,         // padded float4 (PAD=true)
    const float* __restrict__ features,
    const int*   __restrict__ gidx,
    const float* __restrict__ Wpos,
    const float* __restrict__ bposv,
    const float* __restrict__ bn1g, const float* __restrict__ bn1b,
    const float* __restrict__ bn1m, const float* __restrict__ bn1v,
    const float* __restrict__ Wgcm,
    const float* __restrict__ bgcm,
    const float* __restrict__ bn2g, const float* __restrict__ bn2b,
    const float* __restrict__ bn2m, const float* __restrict__ bn2v,
    const float* __restrict__ Watt,
    const float* __restrict__ batt,
    const float* __restrict__ Wout,
    const float* __restrict__ bout,
    const float* __restrict__ lng, const float* __restrict__ lnb,
    float* __restrict__ out)
{
    __shared__ __align__(16) short hbuf[NW][32 * HSTR];       // 36864 B
    __shared__ __align__(16) short resstage[PPB * RSTR];      //  9216 B
    __shared__ __align__(16) short wb2[8 * 64 * 8];           //  8192 B
    __shared__ __align__(16) short wb3[8 * 64 * 8];           //  8192 B

    const int t    = threadIdx.x;
    const int w    = t >> 6;
    const int l    = t & 63;
    const int l15  = l & 15;
    const int quad = l >> 4;
    const int c4   = l15 * 4;

    // ---- XCD batch-affinity swizzle (round-robin wg%8 -> XCD) ----
    // bijective for NWG%8==0: batch-half select + contiguous chunk per XCD
    const int wg  = blockIdx.x;
    const int blk = ((wg & 7) >> 2) * HALF + ((wg >> 3) << 2) + (wg & 3);

    // ---- cooperative weight staging: 16 frag-sets, 2 per wave ----
    {
        #pragma unroll
        for (int u = 0; u < 2; ++u) {
            const int s  = w * 2 + u;          // 0..15
            const int nt = (s >> 1) & 3, ks = s & 1;
            const float* src = (s < 8 ? Wgcm : Wout) + (c4 + nt) * 64 + ks * 32 + quad * 8;
            const f32x4 w0 = *(const f32x4*)src;
            const f32x4 w1 = *(const f32x4*)(src + 4);
            bf16x8 f;
            #pragma unroll
            for (int j = 0; j < 4; ++j) {
                f[j]     = f2bf(w0[j]);
                f[j + 4] = f2bf(w1[j]);
            }
            short* dst = (s < 8 ? wb2 : wb3);
            *(bf16x8*)&dst[((s & 7) * 64 + l) * 8] = f;
        }
    }

    // ---- per-wave constant state ----
    bf16x8 bposf[4];
    #pragma unroll
    for (int nt = 0; nt < 4; ++nt) {
        const int c = c4 + nt;
        #pragma unroll
        for (int j = 0; j < 8; ++j) {
            const int g = quad * 8 + j;
            bposf[nt][j] = f2bf(g < 10 ? Wpos[c * 10 + g] : 0.f);
        }
    }
    f32x4 ps1, pb1, ps2, pb2;
    {
        const f32x4 g1 = *(const f32x4*)(bn1g + c4);
        const f32x4 b1 = *(const f32x4*)(bn1b + c4);
        const f32x4 m1 = *(const f32x4*)(bn1m + c4);
        const f32x4 v1 = *(const f32x4*)(bn1v + c4);
        const f32x4 bp = *(const f32x4*)(bposv + c4);
        const f32x4 g2 = *(const f32x4*)(bn2g + c4);
        const f32x4 b2 = *(const f32x4*)(bn2b + c4);
        const f32x4 m2 = *(const f32x4*)(bn2m + c4);
        const f32x4 v2 = *(const f32x4*)(bn2v + c4);
        const f32x4 bg = *(const f32x4*)(bgcm + c4);
        #pragma unroll
        for (int j = 0; j < 4; ++j) {
            ps1[j] = g1[j] * rsqrtf(v1[j] + EPSF);
            pb1[j] = ps1[j] * (bp[j] - m1[j]) + b1[j];
            ps2[j] = g2[j] * rsqrtf(v2[j] + EPSF);
            pb2[j] = ps2[j] * (bg[j] - m2[j]) + b2[j];
        }
    }
    float wat[2][4];
    #pragma unroll
    for (int mt = 0; mt < 2; ++mt)
        #pragma unroll
        for (int r = 0; r < 4; ++r)
            wat[mt][r] = Watt[mt * 16 + quad * 4 + r];
    const float battv = batt[0];

    const f32x4 zero4 = {0.f, 0.f, 0.f, 0.f};
    short* hb = hbuf[w];
    const int base = blk * PPB + w * PPW;
    const int bb   = ((blk * PPB) >> 14) * N_;   // batch base (blocks don't straddle)

    // ---- pipeline helpers ----
    auto LOADI = [&](int pt, i32x4 (&gi)[2]) {
        gi[0] = *(const i32x4*)(gidx + (size_t)pt * 32 + quad * 4);
        gi[1] = *(const i32x4*)(gidx + (size_t)pt * 32 + 16 + quad * 4);
    };
    // loads everything point pt needs (incl. resid), packs geo A-frags
    auto LOADD = [&](int pt, const i32x4 (&gi)[2],
                     f32x4 (&f4)[2][4], bf16x8 (&ageo)[2], f32x4& resid) {
        #pragma unroll
        for (int mt = 0; mt < 2; ++mt)
            #pragma unroll
            for (int r = 0; r < 4; ++r)
                f4[mt][r] = *(const f32x4*)(features + (size_t)(bb + gi[mt][r]) * 64 + c4);
        resid = *(const f32x4*)(features + (size_t)pt * 64 + c4);
        int gv[2];
        gv[0] = gidx[(size_t)pt * 32 + l15];
        gv[1] = gidx[(size_t)pt * 32 + 16 + l15];
        float xi0, xi1, xi2, px[2], py[2], pz[2];
        if (PAD) {
            const f32x4 x4 = *(const f32x4*)(pp + (size_t)pt * 4);
            xi0 = x4[0]; xi1 = x4[1]; xi2 = x4[2];
            #pragma unroll
            for (int mt = 0; mt < 2; ++mt) {
                const f32x4 p4 = *(const f32x4*)(pp + (size_t)(bb + gv[mt]) * 4);
                px[mt] = p4[0]; py[mt] = p4[1]; pz[mt] = p4[2];
            }
        } else {
            xi0 = points[(size_t)pt * 3];
            xi1 = points[(size_t)pt * 3 + 1];
            xi2 = points[(size_t)pt * 3 + 2];
            #pragma unroll
            for (int mt = 0; mt < 2; ++mt) {
                const float* ppt = points + (size_t)(bb + gv[mt]) * 3;
                px[mt] = ppt[0]; py[mt] = ppt[1]; pz[mt] = ppt[2];
            }
        }
        #pragma unroll
        for (int mt = 0; mt < 2; ++mt) {
            const float dx = xi0 - px[mt], dy = xi1 - py[mt], dz = xi2 - pz[mt];
            const float dist = sqrtf(dx * dx + dy * dy + dz * dz);
            u32x4 u = {0u, 0u, 0u, 0u};
            if (quad == 0) {
                u[0] = pkbf(xi0, xi1); u[1] = pkbf(xi2, px[mt]);
                u[2] = pkbf(py[mt], pz[mt]); u[3] = pkbf(dx, dy);
            } else if (quad == 1) {
                u[0] = pkbf(dz, dist);
            }
            __builtin_memcpy(&ageo[mt], &u, 16);
        }
    };

    // ---- prologue: fill pipeline for points base+0 / base+1 ----
    i32x4 giC[2], giN[2];
    LOADI(base, giC);
    LOADI(base + 1, giN);
    f32x4  f4c[2][4];
    bf16x8 ageoc[2];
    f32x4  residc;
    LOADD(base, giC, f4c, ageoc, residc);

    __syncthreads();   // weight LDS ready

    #pragma unroll 2
    for (int i = 0; i < PPW; ++i) {
        // --- pipeline: next point's data, next-next point's indices ---
        f32x4  f4n[2][4];
        bf16x8 ageon[2];
        f32x4  residn;
        i32x4  giN2[2];
        if (i + 1 < PPW) LOADD(base + i + 1, giN, f4n, ageon, residn);
        if (i + 2 < PPW) LOADI(base + i + 2, giN2);

        // --- pos-MLP MFMA (inputs already in registers) ---
        __builtin_amdgcn_s_setprio(1);
        f32x4 acc1[2][4];
        #pragma unroll
        for (int mt = 0; mt < 2; ++mt)
            #pragma unroll
            for (int nt = 0; nt < 4; ++nt)
                acc1[mt][nt] = __builtin_amdgcn_mfma_f32_16x16x32_bf16(
                    ageoc[mt], bposf[nt], zero4, 0, 0, 0);
        __builtin_amdgcn_s_setprio(0);

        // --- epilogue 1: bn1+relu + feature add, packed converts, b64 writes ---
        #pragma unroll
        for (int mt = 0; mt < 2; ++mt)
            #pragma unroll
            for (int r = 0; r < 4; ++r) {
                const int k = mt * 16 + quad * 4 + r;
                float v[4];
                #pragma unroll
                for (int j = 0; j < 4; ++j)
                    v[j] = f4c[mt][r][j] + fmaxf(ps1[j] * acc1[mt][j][r] + pb1[j], 0.f);
                u32x2 hv = { pkbf(v[0], v[1]), pkbf(v[2], v[3]) };
                *(u32x2*)&hb[k * HSTR + c4] = hv;
            }

        // --- GCM: A-frags from LDS, B-frags from LDS, 16 MFMAs ---
        bf16x8 a2[2][2];
        #pragma unroll
        for (int mt = 0; mt < 2; ++mt)
            #pragma unroll
            for (int ks = 0; ks < 2; ++ks)
                a2[mt][ks] = *(const bf16x8*)&hb[(mt * 16 + l15) * HSTR + ks * 32 + quad * 8];
        __builtin_amdgcn_s_setprio(1);
        f32x4 acc2[2][4];
        #pragma unroll
        for (int nt = 0; nt < 4; ++nt) {
            const bf16x8 b0 = *(const bf16x8*)&wb2[((nt * 2 + 0) * 64 + l) * 8];
            const bf16x8 b1 = *(const bf16x8*)&wb2[((nt * 2 + 1) * 64 + l) * 8];
            #pragma unroll
            for (int mt = 0; mt < 2; ++mt) {
                f32x4 a = __builtin_amdgcn_mfma_f32_16x16x32_bf16(a2[mt][0], b0, zero4, 0, 0, 0);
                acc2[mt][nt] = __builtin_amdgcn_mfma_f32_16x16x32_bf16(a2[mt][1], b1, a, 0, 0, 0);
            }
        }
        __builtin_amdgcn_s_setprio(0);

        // --- epilogue 2: bn2+relu, attention softmax (shift-invariant), pool ---
        float res[4];
        {
            float sp[4], mk[4];
            #pragma unroll
            for (int nt = 0; nt < 4; ++nt) {
                sp[nt] = 0.f; mk[nt] = 0.f;
                #pragma unroll
                for (int mt = 0; mt < 2; ++mt)
                    #pragma unroll
                    for (int r = 0; r < 4; ++r) {
                        const float h2 = fmaxf(ps2[nt] * acc2[mt][nt][r] + pb2[nt], 0.f);
                        sp[nt] += h2 * wat[mt][r];
                        mk[nt] = fmaxf(mk[nt], h2);
                    }
                sp[nt] += __shfl_xor(sp[nt], 16);
                sp[nt] += __shfl_xor(sp[nt], 32);
                mk[nt] = fmaxf(mk[nt], __shfl_xor(mk[nt], 16));
                mk[nt] = fmaxf(mk[nt], __shfl_xor(mk[nt], 32));
            }
            float e[4], s = 0.f;
            #pragma unroll
            for (int nt = 0; nt < 4; ++nt) { e[nt] = __expf(sp[nt] + battv); s += e[nt]; }
            #pragma unroll
            for (int o = 1; o < 16; o <<= 1) s += __shfl_xor(s, o);
            const float inv = 1.f / s;
            #pragma unroll
            for (int nt = 0; nt < 4; ++nt)
                res[nt] = e[nt] * inv * mk[nt] + residc[nt];
        }
        if (quad == 0) {
            u32x2 rv = { pkbf(res[0], res[1]), pkbf(res[2], res[3]) };
            *(u32x2*)&resstage[(w * PPW + i) * RSTR + c4] = rv;
        }

        // --- rotate pipeline registers ---
        if (i + 1 < PPW) {
            #pragma unroll
            for (int mt = 0; mt < 2; ++mt) {
                #pragma unroll
                for (int r = 0; r < 4; ++r) f4c[mt][r] = f4n[mt][r];
                ageoc[mt] = ageon[mt];
            }
            residc = residn;
            if (i + 2 < PPW) { giN[0] = giN2[0]; giN[1] = giN2[1]; }
        }
    }

    __syncthreads();

    // ---------- phase D: batched out-matmul + LayerNorm + relu ----------
    // 4 groups of 16 points; wave w -> group w>>1, LN rows (w&1)*2 + {0,1}
    {
        const int g = w >> 1;
        const f32x4 lngv  = *(const f32x4*)(lng + c4);
        const f32x4 lnbv  = *(const f32x4*)(lnb + c4);
        const f32x4 boutv = *(const f32x4*)(bout + c4);
        bf16x8 a3[2];
        #pragma unroll
        for (int ks = 0; ks < 2; ++ks)
            a3[ks] = *(const bf16x8*)&resstage[(g * 16 + l15) * RSTR + ks * 32 + quad * 8];
        f32x4 acc3[4];
        #pragma unroll
        for (int nt = 0; nt < 4; ++nt) {
            const bf16x8 b0 = *(const bf16x8*)&wb3[((nt * 2 + 0) * 64 + l) * 8];
            const bf16x8 b1 = *(const bf16x8*)&wb3[((nt * 2 + 1) * 64 + l) * 8];
            f32x4 a = __builtin_amdgcn_mfma_f32_16x16x32_bf16(a3[0], b0, zero4, 0, 0, 0);
            acc3[nt] = __builtin_amdgcn_mfma_f32_16x16x32_bf16(a3[1], b1, a, 0, 0, 0);
        }
        #pragma unroll
        for (int u = 0; u < 2; ++u) {
            const int r = (w & 1) * 2 + u;
            float y[4], s = 0.f;
            #pragma unroll
            for (int nt = 0; nt < 4; ++nt) { y[nt] = acc3[nt][r] + boutv[nt]; s += y[nt]; }
            #pragma unroll
            for (int o = 1; o < 16; o <<= 1) s += __shfl_xor(s, o);
            const float mu = s * (1.f / 64.f);
            float dv[4], v2 = 0.f;
            #pragma unroll
            for (int nt = 0; nt < 4; ++nt) { dv[nt] = y[nt] - mu; v2 += dv[nt] * dv[nt]; }
            #pragma unroll
            for (int o = 1; o < 16; o <<= 1) v2 += __shfl_xor(v2, o);
            const float rs = rsqrtf(v2 * (1.f / 64.f) + EPSF);
            const int pto = blk * PPB + g * 16 + quad * 4 + r;
            f32x4 ov;
            #pragma unroll
            for (int nt = 0; nt < 4; ++nt)
                ov[nt] = fmaxf(lngv[nt] * dv[nt] * rs + lnbv[nt], 0.f);
            *(f32x4*)(out + (size_t)pto * 64 + c4) = ov;
        }
    }
}

extern "C" void kernel_launch(void* const* d_in, const int* in_sizes, int n_in,
                              void* d_out, int out_size, void* d_ws, size_t ws_size,
                              hipStream_t stream) {
    const float* points   = (const float*)d_in[0];
    const float* features = (const float*)d_in[1];
    const int*   gidxp    = (const int*)d_in[2];
    const bool   pad      = (ws_size >= PP_BYTES);
    float* pp = (float*)d_ws;
    if (pad) {
        hipLaunchKernelGGL(prep_points, dim3((B_ * N_ + 255) / 256), dim3(256), 0, stream,
                           points, pp);
        hipLaunchKernelGGL((bridgenet11<true>), dim3(NWG), dim3(512), 0, stream,
            points, pp, features, gidxp,
            (const float*)d_in[3],  (const float*)d_in[4],
            (const float*)d_in[5],  (const float*)d_in[6],  (const float*)d_in[7],  (const float*)d_in[8],
            (const float*)d_in[9],  (const float*)d_in[10],
            (const float*)d_in[11], (const float*)d_in[12], (const float*)d_in[13], (const float*)d_in[14],
            (const float*)d_in[15], (const float*)d_in[16],
            (const float*)d_in[17], (const float*)d_in[18],
            (const float*)d_in[19], (const float*)d_in[20],
            (float*)d_out);
    } else {
        hipLaunchKernelGGL((bridgenet11<false>), dim3(NWG), dim3(512), 0, stream,
            points, pp, features, gidxp,
            (const float*)d_in[3],  (const float*)d_in[4],
            (const float*)d_in[5],  (const float*)d_in[6],  (const float*)d_in[7],  (const float*)d_in[8],
            (const float*)d_in[9],  (const float*)d_in[10],
            (const float*)d_in[11], (const float*)d_in[12], (const float*)d_in[13], (const float*)d_in[14],
            (const float*)d_in[15], (const float*)d_in[16],
            (const float*)d_in[17], (const float*)d_in[18],
            (const float*)d_in[19], (const float*)d_in[20],
            (float*)d_out);
    }
}

// Round 6
// 155.114 us; speedup vs baseline: 1.7231x; 1.0526x over previous
//
#include <hip/hip_runtime.h>
#include <hip/hip_bf16.h>

#define EPSF 1e-5f

typedef __attribute__((ext_vector_type(8))) short bf16x8;
typedef __attribute__((ext_vector_type(4))) float f32x4;
typedef __attribute__((ext_vector_type(2))) unsigned int u32x2;
typedef __attribute__((ext_vector_type(4))) unsigned int u32x4;
typedef __attribute__((ext_vector_type(4))) int i32x4;

constexpr int B_ = 2, N_ = 16384;
constexpr int HSTR = 72;   // hbuf row stride (bf16 elems)
constexpr int RSTR = 72;
constexpr int PPW  = 16;   // points per wave   (was 8)
constexpr int NW   = 8;    // waves per block
constexpr int PPB  = 128;  // points per block  (was 64)
constexpr int NWG  = (B_ * N_) / PPB;   // 256 blocks = 1 per CU
constexpr int HALF = NWG / 2;           // blocks per batch
constexpr size_t PP_BYTES = (size_t)B_ * N_ * 16;   // 512 KiB padded points

__device__ __forceinline__ short f2bf(float f) {
    __hip_bfloat16 h = __float2bfloat16(f);
    short s; __builtin_memcpy(&s, &h, 2); return s;
}
// packed f32x2 -> bf16x2 (v_cvt_pk_bf16_f32)
__device__ __forceinline__ unsigned int pkbf(float a, float b) {
    float2 f2; f2.x = a; f2.y = b;
    __hip_bfloat162 h = __float22bfloat162_rn(f2);
    unsigned int u; __builtin_memcpy(&u, &h, 4); return u;
}

// prep: points -> padded float4 (one dwordx4 gather instead of 3 divergent dwords)
__global__ __launch_bounds__(256) void prep_points(
    const float* __restrict__ pts, float* __restrict__ pp)
{
    const int i = blockIdx.x * 256 + threadIdx.x;
    if (i < B_ * N_) {
        f32x4 o = { pts[3 * i], pts[3 * i + 1], pts[3 * i + 2], 0.f };
        ((f32x4*)pp)[i] = o;
    }
}

// bridgenet12 vs bridgenet11 (R5 post-mortem: wave-count model VALIDATED,
// predicted 65 measured 67; resident-wave pool is constant ~6.5 waves/CU):
//  - GEOMETRY: PPW=16, PPB=128, 256 blocks (exactly 1/CU), 2048 waves.
//    Model W: 2048 x (6.3 + 16x2.5) / 1664 = 57 us; if the 1-block/CU grid
//    keeps all waves resident -> ~46 us.
//  - LDS: single wb buffer (8 KB) staged TWICE -- Wgcm before the loop,
//    Wout after the loop barrier (phase-D-only data; restage is 2 vector
//    loads + 16 cvt/lane once per 128 points). Total LDS 63.5 KB < 64 KB.
//  - phase D: 8 groups of 16 points, wave w -> group w, 4 LN rows each.
//  - kept: 2-deep point pipeline, int4 idx loads + LOADI 2-ahead, XCD
//    batch-affinity swizzle, setprio, __launch_bounds__(512,2).
template<bool PAD>
__global__ __launch_bounds__(512, 2) void bridgenet12(
    const float* __restrict__ points,     // raw (PAD=false)
    const float* __restrict__ pp,         // padded float4 (PAD=true)
    const float* __restrict__ features,
    const int*   __restrict__ gidx,
    const float* __restrict__ Wpos,
    const float* __restrict__ bposv,
    const float* __restrict__ bn1g, const float* __restrict__ bn1b,
    const float* __restrict__ bn1m, const float* __restrict__ bn1v,
    const float* __restrict__ Wgcm,
    const float* __restrict__ bgcm,
    const float* __restrict__ bn2g, const float* __restrict__ bn2b,
    const float* __restrict__ bn2m, const float* __restrict__ bn2v,
    const float* __restrict__ Watt,
    const float* __restrict__ batt,
    const float* __restrict__ Wout,
    const float* __restrict__ bout,
    const float* __restrict__ lng, const float* __restrict__ lnb,
    float* __restrict__ out)
{
    __shared__ __align__(16) short hbuf[NW][32 * HSTR];       // 36864 B
    __shared__ __align__(16) short resstage[PPB * RSTR];      // 18432 B
    __shared__ __align__(16) short wb[8 * 64 * 8];            //  8192 B (Wgcm, then Wout)

    const int t    = threadIdx.x;
    const int w    = t >> 6;
    const int l    = t & 63;
    const int l15  = l & 15;
    const int quad = l >> 4;
    const int c4   = l15 * 4;

    // ---- XCD batch-affinity swizzle (round-robin wg%8 -> XCD) ----
    // bijective: XCDs 0-3 own batch 0 (blk 0..127), 4-7 own batch 1
    const int wg  = blockIdx.x;
    const int blk = ((wg & 7) >> 2) * HALF + ((wg >> 3) << 2) + (wg & 3);

    // ---- weight staging pass 1: Wgcm, one frag-set per wave (s = w) ----
    {
        const int nt = w >> 1, ks = w & 1;
        const float* src = Wgcm + (c4 + nt) * 64 + ks * 32 + quad * 8;
        const f32x4 w0 = *(const f32x4*)src;
        const f32x4 w1 = *(const f32x4*)(src + 4);
        bf16x8 f;
        #pragma unroll
        for (int j = 0; j < 4; ++j) {
            f[j]     = f2bf(w0[j]);
            f[j + 4] = f2bf(w1[j]);
        }
        *(bf16x8*)&wb[(w * 64 + l) * 8] = f;
    }

    // ---- per-wave constant state ----
    bf16x8 bposf[4];
    #pragma unroll
    for (int nt = 0; nt < 4; ++nt) {
        const int c = c4 + nt;
        #pragma unroll
        for (int j = 0; j < 8; ++j) {
            const int g = quad * 8 + j;
            bposf[nt][j] = f2bf(g < 10 ? Wpos[c * 10 + g] : 0.f);
        }
    }
    f32x4 ps1, pb1, ps2, pb2;
    {
        const f32x4 g1 = *(const f32x4*)(bn1g + c4);
        const f32x4 b1 = *(const f32x4*)(bn1b + c4);
        const f32x4 m1 = *(const f32x4*)(bn1m + c4);
        const f32x4 v1 = *(const f32x4*)(bn1v + c4);
        const f32x4 bp = *(const f32x4*)(bposv + c4);
        const f32x4 g2 = *(const f32x4*)(bn2g + c4);
        const f32x4 b2 = *(const f32x4*)(bn2b + c4);
        const f32x4 m2 = *(const f32x4*)(bn2m + c4);
        const f32x4 v2 = *(const f32x4*)(bn2v + c4);
        const f32x4 bg = *(const f32x4*)(bgcm + c4);
        #pragma unroll
        for (int j = 0; j < 4; ++j) {
            ps1[j] = g1[j] * rsqrtf(v1[j] + EPSF);
            pb1[j] = ps1[j] * (bp[j] - m1[j]) + b1[j];
            ps2[j] = g2[j] * rsqrtf(v2[j] + EPSF);
            pb2[j] = ps2[j] * (bg[j] - m2[j]) + b2[j];
        }
    }
    float wat[2][4];
    #pragma unroll
    for (int mt = 0; mt < 2; ++mt)
        #pragma unroll
        for (int r = 0; r < 4; ++r)
            wat[mt][r] = Watt[mt * 16 + quad * 4 + r];
    const float battv = batt[0];

    const f32x4 zero4 = {0.f, 0.f, 0.f, 0.f};
    short* hb = hbuf[w];
    const int base = blk * PPB + w * PPW;
    const int bb   = ((blk * PPB) >> 14) * N_;   // batch base (blocks don't straddle)

    // ---- pipeline helpers ----
    auto LOADI = [&](int pt, i32x4 (&gi)[2]) {
        gi[0] = *(const i32x4*)(gidx + (size_t)pt * 32 + quad * 4);
        gi[1] = *(const i32x4*)(gidx + (size_t)pt * 32 + 16 + quad * 4);
    };
    // loads everything point pt needs (incl. resid), packs geo A-frags
    auto LOADD = [&](int pt, const i32x4 (&gi)[2],
                     f32x4 (&f4)[2][4], bf16x8 (&ageo)[2], f32x4& resid) {
        #pragma unroll
        for (int mt = 0; mt < 2; ++mt)
            #pragma unroll
            for (int r = 0; r < 4; ++r)
                f4[mt][r] = *(const f32x4*)(features + (size_t)(bb + gi[mt][r]) * 64 + c4);
        resid = *(const f32x4*)(features + (size_t)pt * 64 + c4);
        int gv[2];
        gv[0] = gidx[(size_t)pt * 32 + l15];
        gv[1] = gidx[(size_t)pt * 32 + 16 + l15];
        float xi0, xi1, xi2, px[2], py[2], pz[2];
        if (PAD) {
            const f32x4 x4 = *(const f32x4*)(pp + (size_t)pt * 4);
            xi0 = x4[0]; xi1 = x4[1]; xi2 = x4[2];
            #pragma unroll
            for (int mt = 0; mt < 2; ++mt) {
                const f32x4 p4 = *(const f32x4*)(pp + (size_t)(bb + gv[mt]) * 4);
                px[mt] = p4[0]; py[mt] = p4[1]; pz[mt] = p4[2];
            }
        } else {
            xi0 = points[(size_t)pt * 3];
            xi1 = points[(size_t)pt * 3 + 1];
            xi2 = points[(size_t)pt * 3 + 2];
            #pragma unroll
            for (int mt = 0; mt < 2; ++mt) {
                const float* ppt = points + (size_t)(bb + gv[mt]) * 3;
                px[mt] = ppt[0]; py[mt] = ppt[1]; pz[mt] = ppt[2];
            }
        }
        #pragma unroll
        for (int mt = 0; mt < 2; ++mt) {
            const float dx = xi0 - px[mt], dy = xi1 - py[mt], dz = xi2 - pz[mt];
            const float dist = sqrtf(dx * dx + dy * dy + dz * dz);
            u32x4 u = {0u, 0u, 0u, 0u};
            if (quad == 0) {
                u[0] = pkbf(xi0, xi1); u[1] = pkbf(xi2, px[mt]);
                u[2] = pkbf(py[mt], pz[mt]); u[3] = pkbf(dx, dy);
            } else if (quad == 1) {
                u[0] = pkbf(dz, dist);
            }
            __builtin_memcpy(&ageo[mt], &u, 16);
        }
    };

    // ---- prologue: fill pipeline for points base+0 / base+1 ----
    i32x4 giC[2], giN[2];
    LOADI(base, giC);
    LOADI(base + 1, giN);
    f32x4  f4c[2][4];
    bf16x8 ageoc[2];
    f32x4  residc;
    LOADD(base, giC, f4c, ageoc, residc);

    __syncthreads();   // weight LDS (Wgcm) ready

    #pragma unroll 2
    for (int i = 0; i < PPW; ++i) {
        // --- pipeline: next point's data, next-next point's indices ---
        f32x4  f4n[2][4];
        bf16x8 ageon[2];
        f32x4  residn;
        i32x4  giN2[2];
        if (i + 1 < PPW) LOADD(base + i + 1, giN, f4n, ageon, residn);
        if (i + 2 < PPW) LOADI(base + i + 2, giN2);

        // --- pos-MLP MFMA (inputs already in registers) ---
        __builtin_amdgcn_s_setprio(1);
        f32x4 acc1[2][4];
        #pragma unroll
        for (int mt = 0; mt < 2; ++mt)
            #pragma unroll
            for (int nt = 0; nt < 4; ++nt)
                acc1[mt][nt] = __builtin_amdgcn_mfma_f32_16x16x32_bf16(
                    ageoc[mt], bposf[nt], zero4, 0, 0, 0);
        __builtin_amdgcn_s_setprio(0);

        // --- epilogue 1: bn1+relu + feature add, packed converts, b64 writes ---
        #pragma unroll
        for (int mt = 0; mt < 2; ++mt)
            #pragma unroll
            for (int r = 0; r < 4; ++r) {
                const int k = mt * 16 + quad * 4 + r;
                float v[4];
                #pragma unroll
                for (int j = 0; j < 4; ++j)
                    v[j] = f4c[mt][r][j] + fmaxf(ps1[j] * acc1[mt][j][r] + pb1[j], 0.f);
                u32x2 hv = { pkbf(v[0], v[1]), pkbf(v[2], v[3]) };
                *(u32x2*)&hb[k * HSTR + c4] = hv;
            }

        // --- GCM: A-frags from LDS, B-frags from LDS, 16 MFMAs ---
        bf16x8 a2[2][2];
        #pragma unroll
        for (int mt = 0; mt < 2; ++mt)
            #pragma unroll
            for (int ks = 0; ks < 2; ++ks)
                a2[mt][ks] = *(const bf16x8*)&hb[(mt * 16 + l15) * HSTR + ks * 32 + quad * 8];
        __builtin_amdgcn_s_setprio(1);
        f32x4 acc2[2][4];
        #pragma unroll
        for (int nt = 0; nt < 4; ++nt) {
            const bf16x8 b0 = *(const bf16x8*)&wb[((nt * 2 + 0) * 64 + l) * 8];
            const bf16x8 b1 = *(const bf16x8*)&wb[((nt * 2 + 1) * 64 + l) * 8];
            #pragma unroll
            for (int mt = 0; mt < 2; ++mt) {
                f32x4 a = __builtin_amdgcn_mfma_f32_16x16x32_bf16(a2[mt][0], b0, zero4, 0, 0, 0);
                acc2[mt][nt] = __builtin_amdgcn_mfma_f32_16x16x32_bf16(a2[mt][1], b1, a, 0, 0, 0);
            }
        }
        __builtin_amdgcn_s_setprio(0);

        // --- epilogue 2: bn2+relu, attention softmax (shift-invariant), pool ---
        float res[4];
        {
            float sp[4], mk[4];
            #pragma unroll
            for (int nt = 0; nt < 4; ++nt) {
                sp[nt] = 0.f; mk[nt] = 0.f;
                #pragma unroll
                for (int mt = 0; mt < 2; ++mt)
                    #pragma unroll
                    for (int r = 0; r < 4; ++r) {
                        const float h2 = fmaxf(ps2[nt] * acc2[mt][nt][r] + pb2[nt], 0.f);
                        sp[nt] += h2 * wat[mt][r];
                        mk[nt] = fmaxf(mk[nt], h2);
                    }
                sp[nt] += __shfl_xor(sp[nt], 16);
                sp[nt] += __shfl_xor(sp[nt], 32);
                mk[nt] = fmaxf(mk[nt], __shfl_xor(mk[nt], 16));
                mk[nt] = fmaxf(mk[nt], __shfl_xor(mk[nt], 32));
            }
            float e[4], s = 0.f;
            #pragma unroll
            for (int nt = 0; nt < 4; ++nt) { e[nt] = __expf(sp[nt] + battv); s += e[nt]; }
            #pragma unroll
            for (int o = 1; o < 16; o <<= 1) s += __shfl_xor(s, o);
            const float inv = 1.f / s;
            #pragma unroll
            for (int nt = 0; nt < 4; ++nt)
                res[nt] = e[nt] * inv * mk[nt] + residc[nt];
        }
        if (quad == 0) {
            u32x2 rv = { pkbf(res[0], res[1]), pkbf(res[2], res[3]) };
            *(u32x2*)&resstage[(w * PPW + i) * RSTR + c4] = rv;
        }

        // --- rotate pipeline registers ---
        if (i + 1 < PPW) {
            #pragma unroll
            for (int mt = 0; mt < 2; ++mt) {
                #pragma unroll
                for (int r = 0; r < 4; ++r) f4c[mt][r] = f4n[mt][r];
                ageoc[mt] = ageon[mt];
            }
            residc = residn;
            if (i + 2 < PPW) { giN[0] = giN2[0]; giN[1] = giN2[1]; }
        }
    }

    __syncthreads();   // loop done: wb2 reads + resstage writes complete

    // ---- weight staging pass 2: Wout into the SAME wb buffer ----
    {
        const int nt = w >> 1, ks = w & 1;
        const float* src = Wout + (c4 + nt) * 64 + ks * 32 + quad * 8;
        const f32x4 w0 = *(const f32x4*)src;
        const f32x4 w1 = *(const f32x4*)(src + 4);
        bf16x8 f;
        #pragma unroll
        for (int j = 0; j < 4; ++j) {
            f[j]     = f2bf(w0[j]);
            f[j + 4] = f2bf(w1[j]);
        }
        *(bf16x8*)&wb[(w * 64 + l) * 8] = f;
    }

    __syncthreads();   // Wout frags ready

    // ---------- phase D: batched out-matmul + LayerNorm + relu ----------
    // 8 groups of 16 points; wave w -> group w, all 4 LN rows
    {
        const f32x4 lngv  = *(const f32x4*)(lng + c4);
        const f32x4 lnbv  = *(const f32x4*)(lnb + c4);
        const f32x4 boutv = *(const f32x4*)(bout + c4);
        bf16x8 a3[2];
        #pragma unroll
        for (int ks = 0; ks < 2; ++ks)
            a3[ks] = *(const bf16x8*)&resstage[(w * 16 + l15) * RSTR + ks * 32 + quad * 8];
        f32x4 acc3[4];
        #pragma unroll
        for (int nt = 0; nt < 4; ++nt) {
            const bf16x8 b0 = *(const bf16x8*)&wb[((nt * 2 + 0) * 64 + l) * 8];
            const bf16x8 b1 = *(const bf16x8*)&wb[((nt * 2 + 1) * 64 + l) * 8];
            f32x4 a = __builtin_amdgcn_mfma_f32_16x16x32_bf16(a3[0], b0, zero4, 0, 0, 0);
            acc3[nt] = __builtin_amdgcn_mfma_f32_16x16x32_bf16(a3[1], b1, a, 0, 0, 0);
        }
        #pragma unroll
        for (int u = 0; u < 4; ++u) {
            float y[4], s = 0.f;
            #pragma unroll
            for (int nt = 0; nt < 4; ++nt) { y[nt] = acc3[nt][u] + boutv[nt]; s += y[nt]; }
            #pragma unroll
            for (int o = 1; o < 16; o <<= 1) s += __shfl_xor(s, o);
            const float mu = s * (1.f / 64.f);
            float dv[4], v2 = 0.f;
            #pragma unroll
            for (int nt = 0; nt < 4; ++nt) { dv[nt] = y[nt] - mu; v2 += dv[nt] * dv[nt]; }
            #pragma unroll
            for (int o = 1; o < 16; o <<= 1) v2 += __shfl_xor(v2, o);
            const float rs = rsqrtf(v2 * (1.f / 64.f) + EPSF);
            const int pto = blk * PPB + w * 16 + quad * 4 + u;
            f32x4 ov;
            #pragma unroll
            for (int nt = 0; nt < 4; ++nt)
                ov[nt] = fmaxf(lngv[nt] * dv[nt] * rs + lnbv[nt], 0.f);
            *(f32x4*)(out + (size_t)pto * 64 + c4) = ov;
        }
    }
}

extern "C" void kernel_launch(void* const* d_in, const int* in_sizes, int n_in,
                              void* d_out, int out_size, void* d_ws, size_t ws_size,
                              hipStream_t stream) {
    const float* points   = (const float*)d_in[0];
    const float* features = (const float*)d_in[1];
    const int*   gidxp    = (const int*)d_in[2];
    const bool   pad      = (ws_size >= PP_BYTES);
    float* pp = (float*)d_ws;
    if (pad) {
        hipLaunchKernelGGL(prep_points, dim3((B_ * N_ + 255) / 256), dim3(256), 0, stream,
                           points, pp);
        hipLaunchKernelGGL((bridgenet12<true>), dim3(NWG), dim3(512), 0, stream,
            points, pp, features, gidxp,
            (const float*)d_in[3],  (const float*)d_in[4],
            (const float*)d_in[5],  (const float*)d_in[6],  (const float*)d_in[7],  (const float*)d_in[8],
            (const float*)d_in[9],  (const float*)d_in[10],
            (const float*)d_in[11], (const float*)d_in[12], (const float*)d_in[13], (const float*)d_in[14],
            (const float*)d_in[15], (const float*)d_in[16],
            (const float*)d_in[17], (const float*)d_in[18],
            (const float*)d_in[19], (const float*)d_in[20],
            (float*)d_out);
    } else {
        hipLaunchKernelGGL((bridgenet12<false>), dim3(NWG), dim3(512), 0, stream,
            points, pp, features, gidxp,
            (const float*)d_in[3],  (const float*)d_in[4],
            (const float*)d_in[5],  (const float*)d_in[6],  (const float*)d_in[7],  (const float*)d_in[8],
            (const float*)d_in[9],  (const float*)d_in[10],
            (const float*)d_in[11], (const float*)d_in[12], (const float*)d_in[13], (const float*)d_in[14],
            (const float*)d_in[15], (const float*)d_in[16],
            (const float*)d_in[17], (const float*)d_in[18],
            (const float*)d_in[19], (const float*)d_in[20],
            (float*)d_out);
    }
}